// Round 5
// baseline (517.709 us; speedup 1.0000x reference)
//
#include <hip/hip_runtime.h>
#include <stdint.h>

// SelfAttention B=2,S=4096,E=1024,H=1024. f32 in, f32 out, bf16 MFMA inside.
// R12: consolidation on measured evidence. Five schedule variants (R7-R11)
//   all hit ~570-600 TF on scores => schedule shape is not the lever at this
//   structure quality. Keep best-of-each: scores = R11 kloop256 (114.8us);
//   qkv/pv = R7 128^2 2-phase 32KB-LDS structure (which beat my 256^2
//   1-block/CU rewrites by ~28us combined) with TWO changes:
//     - __launch_bounds__(256,4) (was 2): VGPR=60, LDS=32KB permit 4-5
//       blocks/CU; m114/m103 implicit cross-block overlap is the only
//       mechanism that has measurably worked on these kernels.
//     - bijective XCD swizzle (grids 1536/512, %8==0) for W/V L2 residency.
// R11: asm ds_read + counted vmcnt -> null; compiler-drain theory falsified.

typedef __bf16 bf16;
typedef __attribute__((ext_vector_type(4))) __bf16 bf16x4;
typedef __attribute__((ext_vector_type(8))) __bf16 bf16x8;
typedef __attribute__((ext_vector_type(4))) float f32x4;

__device__ __forceinline__ void g2l16(const void* g, void* l) {
  __builtin_amdgcn_global_load_lds(
      (const __attribute__((address_space(1))) uint32_t*)g,
      (__attribute__((address_space(3))) uint32_t*)l, 16, 0, 0);
}

__device__ __forceinline__ f32x4 ds_read128(uint32_t addr) {
  f32x4 d;
  asm volatile("ds_read_b128 %0, %1" : "=v"(d) : "v"(addr));
  return d;
}

template <int V> struct IC { static constexpr int value = V; };
template <bool V> struct BC { static constexpr bool value = V; };

template <int N> __device__ __forceinline__ void waitvm() {
  if constexpr (N == 6) asm volatile("s_waitcnt vmcnt(6)" ::: "memory");
  else if constexpr (N == 4) asm volatile("s_waitcnt vmcnt(4)" ::: "memory");
  else if constexpr (N == 0) asm volatile("s_waitcnt vmcnt(0)" ::: "memory");
}

// ---------------- f32 -> bf16 converters -----------------------------------
__global__ __launch_bounds__(256) void cvt_f32_bf16(
    const float* __restrict__ src, bf16* __restrict__ dst, int n) {
  const int i = (blockIdx.x * 256 + threadIdx.x) * 8;
  if (i >= n) return;
  f32x4 a = *(const f32x4*)(src + i);
  f32x4 b = *(const f32x4*)(src + i + 4);
  bf16x8 o;
#pragma unroll
  for (int e = 0; e < 4; ++e) { o[e] = (bf16)a[e]; o[4 + e] = (bf16)b[e]; }
  *(bf16x8*)(dst + i) = o;
}

__global__ __launch_bounds__(256) void cvt_w3(
    const float* __restrict__ Wq, const float* __restrict__ Wk,
    const float* __restrict__ Wv, bf16* __restrict__ dst) {
  const int i = (blockIdx.x * 256 + threadIdx.x) * 8;
  const int seg = i >> 20;
  const int off = i & 1048575;
  const float* src = (seg == 0) ? Wq : (seg == 1) ? Wk : Wv;
  f32x4 a = *(const f32x4*)(src + off);
  f32x4 b = *(const f32x4*)(src + off + 4);
  bf16x8 o;
#pragma unroll
  for (int e = 0; e < 4; ++e) { o[e] = (bf16)a[e]; o[4 + e] = (bf16)b[e]; }
  *(bf16x8*)(dst + i) = o;
}

// ======================= kloop256: BM=256 x BN=256, BK=64 (scores) =========
// R11 form: asm ds_read_b128, counted vmcnt(6), 4 phases/K-tile, 2 buffers.
template <int NT>
__device__ __forceinline__ void kloop256(
    const bf16* __restrict__ Ag, const bf16* __restrict__ Bg, const int KA,
    const int KB, bf16* lds, f32x4 (&acc)[8][4]) {
  const int tid = threadIdx.x;
  const int lane = tid & 63;
  const int wave = tid >> 6;
  const int l15 = lane & 15, quad = lane >> 4;
  const int wrow = (wave >> 2) * 128;
  const int wcol = (wave & 3) * 64;
  const int srow = tid >> 3;
  const int scol = ((tid & 7) ^ (srow & 7)) * 8;
  const int swz = l15 & 7;

  const uint32_t lds_u = (uint32_t)(uintptr_t)lds;
  const uint32_t a_l15 = lds_u + (uint32_t)((wrow + l15) * 128);
  const uint32_t b_l15 = lds_u + 32768u + (uint32_t)((wcol + l15) * 128);
  const uint32_t ck0 = (uint32_t)(((quad) ^ swz) * 16);
  const uint32_t ck1 = (uint32_t)(((4 + quad) ^ swz) * 16);

  auto stg = [&](int t, int h) {
    bf16* base = lds + (t & 1) * 32768;
    if (h == 0) {
      const bf16* g = Bg + (size_t)srow * KB + t * 64 + scol;
      g2l16(g, base + 16384 + tid * 8);
      g2l16(g + (size_t)64 * KB, base + 16384 + tid * 8 + 4096);
    } else if (h == 1) {
      const bf16* g = Bg + (size_t)(128 + srow) * KB + t * 64 + scol;
      g2l16(g, base + 24576 + tid * 8);
      g2l16(g + (size_t)64 * KB, base + 24576 + tid * 8 + 4096);
    } else if (h == 2) {
      const bf16* g = Ag + (size_t)srow * KA + t * 64 + scol;
      g2l16(g, base + tid * 8);
      g2l16(g + (size_t)128 * KA, base + tid * 8 + 8192);
    } else {
      const bf16* g = Ag + (size_t)(64 + srow) * KA + t * 64 + scol;
      g2l16(g, base + 4096 + tid * 8);
      g2l16(g + (size_t)128 * KA, base + 4096 + tid * 8 + 8192);
    }
  };

  f32x4 brf[2][4];
  auto phase = [&](int t, auto qc, int st, int sh, auto dsc, auto vmc) {
    constexpr int q = decltype(qc)::value;
    constexpr bool ds = decltype(dsc)::value;
    constexpr int vm = decltype(vmc)::value;
    const uint32_t bb = (t & 1) ? 65536u : 0u;
    f32x4 ar[2][2];
#pragma unroll
    for (int i = 0; i < 2; ++i) {
      ar[i][0] = ds_read128(a_l15 + bb + (uint32_t)((2 * q + i) * 2048) + ck0);
      ar[i][1] = ds_read128(a_l15 + bb + (uint32_t)((2 * q + i) * 2048) + ck1);
    }
    if constexpr (q == 0) {
#pragma unroll
      for (int j = 0; j < 4; ++j) {
        brf[0][j] = ds_read128(b_l15 + bb + (uint32_t)(j * 2048) + ck0);
        brf[1][j] = ds_read128(b_l15 + bb + (uint32_t)(j * 2048) + ck1);
      }
    }
    if constexpr (ds) stg(st, sh);
    __builtin_amdgcn_s_barrier();
    asm volatile("s_waitcnt lgkmcnt(0)" ::: "memory");
    __builtin_amdgcn_sched_barrier(0);
    __builtin_amdgcn_s_setprio(1);
#pragma unroll
    for (int ks = 0; ks < 2; ++ks)
#pragma unroll
      for (int i = 0; i < 2; ++i)
#pragma unroll
        for (int j = 0; j < 4; ++j)
          acc[2 * q + i][j] = __builtin_amdgcn_mfma_f32_16x16x32_bf16(
              __builtin_bit_cast(bf16x8, ar[i][ks]),
              __builtin_bit_cast(bf16x8, brf[ks][j]),
              acc[2 * q + i][j], 0, 0, 0);
    __builtin_amdgcn_s_setprio(0);
    waitvm<vm>();
    __builtin_amdgcn_s_barrier();
  };

  stg(0, 0); stg(0, 1); stg(0, 2); stg(0, 3);
  stg(1, 0); stg(1, 1); stg(1, 2);
  asm volatile("s_waitcnt vmcnt(6)" ::: "memory");
  __builtin_amdgcn_s_barrier();

  constexpr int NI = NT / 2;
#pragma unroll 1
  for (int u = 0; u < NI - 1; ++u) {
    const int t0 = 2 * u, t1 = t0 + 1;
    phase(t0, IC<0>{}, t1, 3, BC<true>{}, IC<-1>{});
    phase(t0, IC<1>{}, t0 + 2, 0, BC<true>{}, IC<-1>{});
    phase(t0, IC<2>{}, t0 + 2, 1, BC<true>{}, IC<-1>{});
    phase(t0, IC<3>{}, t0 + 2, 2, BC<true>{}, IC<6>{});
    phase(t1, IC<0>{}, t0 + 2, 3, BC<true>{}, IC<-1>{});
    phase(t1, IC<1>{}, t0 + 3, 0, BC<true>{}, IC<-1>{});
    phase(t1, IC<2>{}, t0 + 3, 1, BC<true>{}, IC<-1>{});
    phase(t1, IC<3>{}, t0 + 3, 2, BC<true>{}, IC<6>{});
  }
  {
    const int t0 = NT - 2, t1 = NT - 1;
    phase(t0, IC<0>{}, t1, 3, BC<true>{}, IC<-1>{});
    phase(t0, IC<1>{}, 0, 0, BC<false>{}, IC<-1>{});
    phase(t0, IC<2>{}, 0, 0, BC<false>{}, IC<-1>{});
    phase(t0, IC<3>{}, 0, 0, BC<false>{}, IC<0>{});
    phase(t1, IC<0>{}, 0, 0, BC<false>{}, IC<-1>{});
    phase(t1, IC<1>{}, 0, 0, BC<false>{}, IC<-1>{});
    phase(t1, IC<2>{}, 0, 0, BC<false>{}, IC<-1>{});
    phase(t1, IC<3>{}, 0, 0, BC<false>{}, IC<-1>{});
  }
}

// ---------------- fused QKV GEMM (R7 128^2 structure, occ-bumped) ----------
// grid (64, 24): x = m-tile (128 rows), y = which*8 + n-tile (128 cols).
__global__ __launch_bounds__(256, 4) void gemm_qkv(
    const bf16* __restrict__ Xb, const bf16* __restrict__ Wb3,
    const float* __restrict__ bq, const float* __restrict__ bk,
    const float* __restrict__ bv, bf16* __restrict__ QK,
    bf16* __restrict__ Vt)
{
  constexpr int K = 1024, N = 1024;
  __shared__ __align__(16) bf16 ldsA[128 * 64];
  __shared__ __align__(16) bf16 ldsB[128 * 64];

  const int tid  = threadIdx.x;
  const int lane = tid & 63;
  const int wave = tid >> 6;
  // XCD swizzle: 1536 blocks, 192 per XCD.
  const int bid = blockIdx.y * 64 + blockIdx.x;
  const int sb = (bid & 7) * 192 + (bid >> 3);
  const int bx = sb & 63, by = sb >> 6;
  const int which = by >> 3;
  const int n0 = (by & 7) * 128;
  const int m0 = bx * 128;
  const bf16* Bt = Wb3 + (size_t)which * 1048576;
  const float* bias = (which == 0) ? bq : ((which == 1) ? bk : bv);

  const int l15  = lane & 15;
  const int quad = lane >> 4;
  const int wm = (wave >> 1) * 64;
  const int wn = (wave & 1) * 64;
  const int sw = l15 & 7;

  f32x4 acc[4][4];
#pragma unroll
  for (int i = 0; i < 4; ++i)
#pragma unroll
    for (int j = 0; j < 4; ++j) acc[i][j] = f32x4{0.f, 0.f, 0.f, 0.f};

  const int srow = tid >> 3;
  const int scol = ((tid & 7) ^ (srow & 7)) * 8;
  const size_t a_base = (size_t)(m0 + srow) * K + scol;
  const size_t b_base = (size_t)(n0 + srow) * K + scol;
  const int lds_off = tid * 8;

  for (int kt = 0; kt < K; kt += 64) {
    const bf16* ga = Xb + a_base + kt;
    const bf16* gb = Bt + b_base + kt;
#pragma unroll
    for (int it = 0; it < 4; ++it) {
      g2l16(ga + (size_t)(it * 32) * K, &ldsA[lds_off + it * 2048]);
      g2l16(gb + (size_t)(it * 32) * K, &ldsB[lds_off + it * 2048]);
    }
    __syncthreads();
#pragma unroll
    for (int ks = 0; ks < 2; ++ks) {
      const int ch = ks * 4 + quad;
      bf16x8 af[4], bfg[4];
#pragma unroll
      for (int i = 0; i < 4; ++i)
        af[i] = *(const bf16x8*)&ldsA[(wm + i * 16 + l15) * 64 + (ch ^ sw) * 8];
#pragma unroll
      for (int j = 0; j < 4; ++j)
        bfg[j] = *(const bf16x8*)&ldsB[(wn + j * 16 + l15) * 64 + (ch ^ sw) * 8];
#pragma unroll
      for (int i = 0; i < 4; ++i)
#pragma unroll
        for (int j = 0; j < 4; ++j)
          acc[i][j] = __builtin_amdgcn_mfma_f32_16x16x32_bf16(
              af[i], bfg[j], acc[i][j], 0, 0, 0);
    }
    __syncthreads();
  }

  // C/D layout: col = lane&15, row = quad*4 + reg [m89/m91]
  if (which < 2) {
    bf16* C = QK + (size_t)which * (size_t)(8192 * 1024);
#pragma unroll
    for (int i = 0; i < 4; ++i) {
#pragma unroll
      for (int j = 0; j < 4; ++j) {
        const int r = m0 + wm + i * 16 + quad * 4;
        const int c = n0 + wn + j * 16 + l15;
        const float bvv = bias[c];
        f32x4 v = acc[i][j];
#pragma unroll
        for (int reg = 0; reg < 4; ++reg)
          C[(size_t)(r + reg) * N + c] = (bf16)(v[reg] + bvv);
      }
    }
  } else {
#pragma unroll
    for (int i = 0; i < 4; ++i) {
#pragma unroll
      for (int j = 0; j < 4; ++j) {
        const int r = m0 + wm + i * 16 + quad * 4;  // b*4096+s
        const int c = n0 + wn + j * 16 + l15;       // h
        const int b = r >> 12, s = r & 4095;
        const float bvv = bias[c];
        f32x4 v = acc[i][j];
        bf16x4 o;
#pragma unroll
        for (int reg = 0; reg < 4; ++reg) o[reg] = (bf16)(v[reg] + bvv);
        *(bf16x4*)&Vt[((size_t)(b * 1024 + c)) * 4096 + s] = o;
      }
    }
  }
}

// ---------------- scores GEMM + fused exp/mask/row-sum (R11) ---------------
// grid (32, 16): x = m-tile (256), y = n-tile (256).
__global__ __launch_bounds__(512, 2) void gemm_scores(
    const bf16* __restrict__ Q, const bf16* __restrict__ Kb,
    const int* __restrict__ mask, bf16* __restrict__ P,
    float* __restrict__ row_sum) {
  __shared__ __align__(16) bf16 lds[2 * 32768];  // 128 KiB
  const int bid = blockIdx.y * 32 + blockIdx.x;
  const int sb = (bid & 7) * 64 + (bid >> 3);
  const int bx = sb & 31, by = sb >> 5;
  const int m0 = bx * 256;
  const int n0 = by * 256;
  const int batch = m0 >> 12;
  const bf16* Ag = Q + (size_t)m0 * 1024;
  const bf16* Bg = Kb + (size_t)batch * (size_t)(4096 * 1024) +
                   (size_t)n0 * 1024;

  f32x4 acc[8][4];
#pragma unroll
  for (int i = 0; i < 8; ++i)
#pragma unroll
    for (int j = 0; j < 4; ++j) acc[i][j] = f32x4{0.f, 0.f, 0.f, 0.f};

  kloop256<16>(Ag, Bg, 1024, 1024, lds, acc);

  const int lane = threadIdx.x & 63, wave = threadIdx.x >> 6;
  const int l15 = lane & 15, quad = lane >> 4;
  const int wrow = (wave >> 2) * 128, wcol = (wave & 3) * 64;

#pragma unroll
  for (int i = 0; i < 8; ++i) {
    const int r = m0 + wrow + i * 16 + quad * 4;
    f32x4 rsum = f32x4{0.f, 0.f, 0.f, 0.f};
#pragma unroll
    for (int j = 0; j < 4; ++j) {
      const int c = n0 + wcol + j * 16 + l15;
      f32x4 v = acc[i][j];
#pragma unroll
      for (int reg = 0; reg < 4; ++reg) {
        float e = __expf(v[reg] * 0.03125f);
        if (mask[(size_t)(r + reg) * 4096 + c] == 0) e = 0.f;
        P[(size_t)(r + reg) * 4096 + c] = (bf16)e;
        rsum[reg] += e;
      }
    }
#pragma unroll
    for (int off = 1; off < 16; off <<= 1) {
#pragma unroll
      for (int reg = 0; reg < 4; ++reg)
        rsum[reg] += __shfl_xor(rsum[reg], off);
    }
    if (l15 == 0) {
#pragma unroll
      for (int reg = 0; reg < 4; ++reg)
        atomicAdd(&row_sum[r + reg], rsum[reg]);
    }
  }
}

// ---------------- PV GEMM (R7 128^2 structure, occ-bumped) -----------------
// out[m,h] = (P[m,:]·Vt[h,:]) / row_sum[m].  grid (64, 8).
__global__ __launch_bounds__(256, 4) void gemm_pv(
    const bf16* __restrict__ A, const bf16* __restrict__ Bt,
    const float* __restrict__ row_sum, float* __restrict__ C)
{
  constexpr int N = 1024, K = 4096;
  __shared__ __align__(16) bf16 ldsA[128 * 64];
  __shared__ __align__(16) bf16 ldsB[128 * 64];

  const int tid  = threadIdx.x;
  const int lane = tid & 63;
  const int wave = tid >> 6;
  // XCD swizzle: 512 blocks, 64 per XCD (V-panel L2-resident, P streamed).
  const int bid = blockIdx.y * 64 + blockIdx.x;
  const int sb = (bid & 7) * 64 + (bid >> 3);
  const int bx = sb & 63, by = sb >> 6;
  const int m0 = bx * 128;
  const int n0 = by * 128;
  const int batch = m0 >> 12;
  const bf16* Btb = Bt + (size_t)batch * (size_t)(1024 * 4096);

  const int l15  = lane & 15;
  const int quad = lane >> 4;
  const int wm = (wave >> 1) * 64;
  const int wn = (wave & 1) * 64;
  const int sw = l15 & 7;

  f32x4 acc[4][4];
#pragma unroll
  for (int i = 0; i < 4; ++i)
#pragma unroll
    for (int j = 0; j < 4; ++j) acc[i][j] = f32x4{0.f, 0.f, 0.f, 0.f};

  const int srow = tid >> 3;
  const int scol = ((tid & 7) ^ (srow & 7)) * 8;
  const size_t a_base = (size_t)(m0 + srow) * K + scol;
  const size_t b_base = (size_t)(n0 + srow) * K + scol;
  const int lds_off = tid * 8;

  for (int kt = 0; kt < K; kt += 64) {
    const bf16* ga = A + a_base + kt;
    const bf16* gb = Btb + b_base + kt;
#pragma unroll
    for (int it = 0; it < 4; ++it) {
      g2l16(ga + (size_t)(it * 32) * K, &ldsA[lds_off + it * 2048]);
      g2l16(gb + (size_t)(it * 32) * K, &ldsB[lds_off + it * 2048]);
    }
    __syncthreads();
#pragma unroll
    for (int ks = 0; ks < 2; ++ks) {
      const int ch = ks * 4 + quad;
      bf16x8 af[4], bfg[4];
#pragma unroll
      for (int i = 0; i < 4; ++i)
        af[i] = *(const bf16x8*)&ldsA[(wm + i * 16 + l15) * 64 + (ch ^ sw) * 8];
#pragma unroll
      for (int j = 0; j < 4; ++j)
        bfg[j] = *(const bf16x8*)&ldsB[(wn + j * 16 + l15) * 64 + (ch ^ sw) * 8];
#pragma unroll
      for (int i = 0; i < 4; ++i)
#pragma unroll
        for (int j = 0; j < 4; ++j)
          acc[i][j] = __builtin_amdgcn_mfma_f32_16x16x32_bf16(
              af[i], bfg[j], acc[i][j], 0, 0, 0);
    }
    __syncthreads();
  }

#pragma unroll
  for (int i = 0; i < 4; ++i) {
    const int r = m0 + wm + i * 16 + quad * 4;
    f32x4 inv;
#pragma unroll
    for (int reg = 0; reg < 4; ++reg) inv[reg] = 1.0f / row_sum[r + reg];
#pragma unroll
    for (int j = 0; j < 4; ++j) {
      const int c = n0 + wn + j * 16 + l15;
      f32x4 v = acc[i][j];
#pragma unroll
      for (int reg = 0; reg < 4; ++reg)
        C[(size_t)(r + reg) * N + c] = v[reg] * inv[reg];
    }
  }
}

extern "C" void kernel_launch(void* const* d_in, const int* in_sizes, int n_in,
                              void* d_out, int out_size, void* d_ws,
                              size_t ws_size, hipStream_t stream) {
  const float* X   = (const float*)d_in[0];
  const int* mask  = (const int*)d_in[1];
  const float* Wq  = (const float*)d_in[2];
  const float* bq  = (const float*)d_in[3];
  const float* Wk  = (const float*)d_in[4];
  const float* bk  = (const float*)d_in[5];
  const float* Wv  = (const float*)d_in[6];
  const float* bv  = (const float*)d_in[7];
  float* out = (float*)d_out;

  // ws layout (128 MiB): [0,16M) Q  [16M,32M) K  [32M,48M) X_bf
  //   [48M,64M) Vt  [64M,128M) Sc/P (first 6 MiB aliased by W_bf).
  //   row_sum (32 KB) aliases X_bf (dead after gemm_qkv).
  const size_t QKV_ELEMS = (size_t)8192 * 1024;
  bf16* Q    = (bf16*)d_ws;
  bf16* Kb   = Q + QKV_ELEMS;
  bf16* X_bf = Kb + QKV_ELEMS;
  bf16* Vt   = X_bf + QKV_ELEMS;
  bf16* Sc   = Vt + QKV_ELEMS;
  bf16* W_bf = Sc;
  float* row_sum = (float*)X_bf;  // 8192 floats

  cvt_f32_bf16<<<dim3(4096), dim3(256), 0, stream>>>(X, X_bf, 8388608);
  cvt_w3<<<dim3(1536), dim3(256), 0, stream>>>(Wq, Wk, Wv, W_bf);
  gemm_qkv<<<dim3(64, 24), dim3(256), 0, stream>>>(X_bf, W_bf, bq, bk, bv, Q,
                                                   Vt);
  hipMemsetAsync(row_sum, 0, 8192 * sizeof(float), stream);
  gemm_scores<<<dim3(32, 16), dim3(512), 0, stream>>>(Q, Kb, mask, Sc,
                                                      row_sum);
  gemm_pv<<<dim3(64, 8), dim3(256), 0, stream>>>(Sc, Vt, row_sum, out);
}

// Round 7
// 456.320 us; speedup vs baseline: 1.1345x; 1.1345x over previous
//
#include <hip/hip_runtime.h>
#include <stdint.h>

// SelfAttention B=2,S=4096,E=1024,H=1024. f32 in, f32 out, bf16 MFMA inside.
// R14 == R13 resubmit (R13 died to container infra, no counters). One
//   defensive change: bitmask moved from d_out into ws (X_bf region, dead
//   after gemm_qkv; +64KB past row_sum). pack_mask reordered after gemm_qkv.
// R13: memory-term surgery (model: dur = MFMA-floor + non-overlapped memory
//   phases; schedule shape R7-R11 all null because epilogue/panel traffic
//   dominates the stalls, not K-loop shape).
//   - pack_mask: int32 mask -> 1-bit bitmask via __ballot (134 MB -> 4 MB in
//     scores' epilogue burst).
//   - pv/qkv: m-grouped bijective XCD swizzle (all n-tiles of an A-panel on
//     one XCD consecutively -> panel L2-filled once per XCD, not 8x/24x).
//     pv on R7-proven (256,2) 128^2 structure (R12's occ-4 + bad swizzle
//     gave FETCH 294 MB, 148 us).
//   - scores: R11 kloop256 (best measured) + bitmask epilogue (4 broadcast
//     u64 loads per i-iter instead of 128 scattered dwords).

typedef __bf16 bf16;
typedef __attribute__((ext_vector_type(4))) __bf16 bf16x4;
typedef __attribute__((ext_vector_type(8))) __bf16 bf16x8;
typedef __attribute__((ext_vector_type(4))) float f32x4;

__device__ __forceinline__ void g2l16(const void* g, void* l) {
  __builtin_amdgcn_global_load_lds(
      (const __attribute__((address_space(1))) uint32_t*)g,
      (__attribute__((address_space(3))) uint32_t*)l, 16, 0, 0);
}

__device__ __forceinline__ f32x4 ds_read128(uint32_t addr) {
  f32x4 d;
  asm volatile("ds_read_b128 %0, %1" : "=v"(d) : "v"(addr));
  return d;
}

template <int V> struct IC { static constexpr int value = V; };
template <bool V> struct BC { static constexpr bool value = V; };

template <int N> __device__ __forceinline__ void waitvm() {
  if constexpr (N == 6) asm volatile("s_waitcnt vmcnt(6)" ::: "memory");
  else if constexpr (N == 4) asm volatile("s_waitcnt vmcnt(4)" ::: "memory");
  else if constexpr (N == 0) asm volatile("s_waitcnt vmcnt(0)" ::: "memory");
}

// ---------------- f32 -> bf16 converters -----------------------------------
__global__ __launch_bounds__(256) void cvt_f32_bf16(
    const float* __restrict__ src, bf16* __restrict__ dst, int n) {
  const int i = (blockIdx.x * 256 + threadIdx.x) * 8;
  if (i >= n) return;
  f32x4 a = *(const f32x4*)(src + i);
  f32x4 b = *(const f32x4*)(src + i + 4);
  bf16x8 o;
#pragma unroll
  for (int e = 0; e < 4; ++e) { o[e] = (bf16)a[e]; o[4 + e] = (bf16)b[e]; }
  *(bf16x8*)(dst + i) = o;
}

__global__ __launch_bounds__(256) void cvt_w3(
    const float* __restrict__ Wq, const float* __restrict__ Wk,
    const float* __restrict__ Wv, bf16* __restrict__ dst) {
  const int i = (blockIdx.x * 256 + threadIdx.x) * 8;
  const int seg = i >> 20;
  const int off = i & 1048575;
  const float* src = (seg == 0) ? Wq : (seg == 1) ? Wk : Wv;
  f32x4 a = *(const f32x4*)(src + off);
  f32x4 b = *(const f32x4*)(src + off + 4);
  bf16x8 o;
#pragma unroll
  for (int e = 0; e < 4; ++e) { o[e] = (bf16)a[e]; o[4 + e] = (bf16)b[e]; }
  *(bf16x8*)(dst + i) = o;
}

// ---------------- mask -> bitmask (1 bit per element) ----------------------
// 33.5M int32 -> 4 MB bits. Wave handles 64 consecutive elems per iter via
// __ballot; lane 0 stores the u64 word. Coalesced loads, ~HBM-bound.
__global__ __launch_bounds__(256) void pack_mask(
    const int* __restrict__ m, unsigned long long* __restrict__ bm,
    int n) {
  const int gw = (blockIdx.x * 256 + threadIdx.x) >> 6;  // global wave id
  const int lane = threadIdx.x & 63;
  const int nw = (2048 * 256) >> 6;
  for (int base = gw * 64; base < n; base += nw * 64) {
    const int v = m[base + lane];
    const unsigned long long b = __ballot(v != 0);
    if (lane == 0) bm[base >> 6] = b;
  }
}

// ======================= kloop256: BM=256 x BN=256, BK=64 (scores) =========
// R11 form: asm ds_read_b128, counted vmcnt(6), 4 phases/K-tile, 2 buffers.
template <int NT>
__device__ __forceinline__ void kloop256(
    const bf16* __restrict__ Ag, const bf16* __restrict__ Bg, const int KA,
    const int KB, bf16* lds, f32x4 (&acc)[8][4]) {
  const int tid = threadIdx.x;
  const int lane = tid & 63;
  const int wave = tid >> 6;
  const int l15 = lane & 15, quad = lane >> 4;
  const int wrow = (wave >> 2) * 128;
  const int wcol = (wave & 3) * 64;
  const int srow = tid >> 3;
  const int scol = ((tid & 7) ^ (srow & 7)) * 8;
  const int swz = l15 & 7;

  const uint32_t lds_u = (uint32_t)(uintptr_t)lds;
  const uint32_t a_l15 = lds_u + (uint32_t)((wrow + l15) * 128);
  const uint32_t b_l15 = lds_u + 32768u + (uint32_t)((wcol + l15) * 128);
  const uint32_t ck0 = (uint32_t)(((quad) ^ swz) * 16);
  const uint32_t ck1 = (uint32_t)(((4 + quad) ^ swz) * 16);

  auto stg = [&](int t, int h) {
    bf16* base = lds + (t & 1) * 32768;
    if (h == 0) {
      const bf16* g = Bg + (size_t)srow * KB + t * 64 + scol;
      g2l16(g, base + 16384 + tid * 8);
      g2l16(g + (size_t)64 * KB, base + 16384 + tid * 8 + 4096);
    } else if (h == 1) {
      const bf16* g = Bg + (size_t)(128 + srow) * KB + t * 64 + scol;
      g2l16(g, base + 24576 + tid * 8);
      g2l16(g + (size_t)64 * KB, base + 24576 + tid * 8 + 4096);
    } else if (h == 2) {
      const bf16* g = Ag + (size_t)srow * KA + t * 64 + scol;
      g2l16(g, base + tid * 8);
      g2l16(g + (size_t)128 * KA, base + tid * 8 + 8192);
    } else {
      const bf16* g = Ag + (size_t)(64 + srow) * KA + t * 64 + scol;
      g2l16(g, base + 4096 + tid * 8);
      g2l16(g + (size_t)128 * KA, base + 4096 + tid * 8 + 8192);
    }
  };

  f32x4 brf[2][4];
  auto phase = [&](int t, auto qc, int st, int sh, auto dsc, auto vmc) {
    constexpr int q = decltype(qc)::value;
    constexpr bool ds = decltype(dsc)::value;
    constexpr int vm = decltype(vmc)::value;
    const uint32_t bb = (t & 1) ? 65536u : 0u;
    f32x4 ar[2][2];
#pragma unroll
    for (int i = 0; i < 2; ++i) {
      ar[i][0] = ds_read128(a_l15 + bb + (uint32_t)((2 * q + i) * 2048) + ck0);
      ar[i][1] = ds_read128(a_l15 + bb + (uint32_t)((2 * q + i) * 2048) + ck1);
    }
    if constexpr (q == 0) {
#pragma unroll
      for (int j = 0; j < 4; ++j) {
        brf[0][j] = ds_read128(b_l15 + bb + (uint32_t)(j * 2048) + ck0);
        brf[1][j] = ds_read128(b_l15 + bb + (uint32_t)(j * 2048) + ck1);
      }
    }
    if constexpr (ds) stg(st, sh);
    __builtin_amdgcn_s_barrier();
    asm volatile("s_waitcnt lgkmcnt(0)" ::: "memory");
    __builtin_amdgcn_sched_barrier(0);
    __builtin_amdgcn_s_setprio(1);
#pragma unroll
    for (int ks = 0; ks < 2; ++ks)
#pragma unroll
      for (int i = 0; i < 2; ++i)
#pragma unroll
        for (int j = 0; j < 4; ++j)
          acc[2 * q + i][j] = __builtin_amdgcn_mfma_f32_16x16x32_bf16(
              __builtin_bit_cast(bf16x8, ar[i][ks]),
              __builtin_bit_cast(bf16x8, brf[ks][j]),
              acc[2 * q + i][j], 0, 0, 0);
    __builtin_amdgcn_s_setprio(0);
    waitvm<vm>();
    __builtin_amdgcn_s_barrier();
  };

  stg(0, 0); stg(0, 1); stg(0, 2); stg(0, 3);
  stg(1, 0); stg(1, 1); stg(1, 2);
  asm volatile("s_waitcnt vmcnt(6)" ::: "memory");
  __builtin_amdgcn_s_barrier();

  constexpr int NI = NT / 2;
#pragma unroll 1
  for (int u = 0; u < NI - 1; ++u) {
    const int t0 = 2 * u, t1 = t0 + 1;
    phase(t0, IC<0>{}, t1, 3, BC<true>{}, IC<-1>{});
    phase(t0, IC<1>{}, t0 + 2, 0, BC<true>{}, IC<-1>{});
    phase(t0, IC<2>{}, t0 + 2, 1, BC<true>{}, IC<-1>{});
    phase(t0, IC<3>{}, t0 + 2, 2, BC<true>{}, IC<6>{});
    phase(t1, IC<0>{}, t0 + 2, 3, BC<true>{}, IC<-1>{});
    phase(t1, IC<1>{}, t0 + 3, 0, BC<true>{}, IC<-1>{});
    phase(t1, IC<2>{}, t0 + 3, 1, BC<true>{}, IC<-1>{});
    phase(t1, IC<3>{}, t0 + 3, 2, BC<true>{}, IC<6>{});
  }
  {
    const int t0 = NT - 2, t1 = NT - 1;
    phase(t0, IC<0>{}, t1, 3, BC<true>{}, IC<-1>{});
    phase(t0, IC<1>{}, 0, 0, BC<false>{}, IC<-1>{});
    phase(t0, IC<2>{}, 0, 0, BC<false>{}, IC<-1>{});
    phase(t0, IC<3>{}, 0, 0, BC<false>{}, IC<0>{});
    phase(t1, IC<0>{}, 0, 0, BC<false>{}, IC<-1>{});
    phase(t1, IC<1>{}, 0, 0, BC<false>{}, IC<-1>{});
    phase(t1, IC<2>{}, 0, 0, BC<false>{}, IC<-1>{});
    phase(t1, IC<3>{}, 0, 0, BC<false>{}, IC<-1>{});
  }
}

// ---------------- fused QKV GEMM (R7 structure + m-grouped XCD swizzle) ----
// 1536 blocks: xcd=d%8, slot=d/8; g = xcd*8 + slot/24 (m-tile), c = slot%24
// (which*8 + n-tile). All 24 n-blocks of an X-panel run on one XCD.
__global__ __launch_bounds__(256, 2) void gemm_qkv(
    const bf16* __restrict__ Xb, const bf16* __restrict__ Wb3,
    const float* __restrict__ bq, const float* __restrict__ bk,
    const float* __restrict__ bv, bf16* __restrict__ QK,
    bf16* __restrict__ Vt)
{
  constexpr int K = 1024, N = 1024;
  __shared__ __align__(16) bf16 ldsA[128 * 64];
  __shared__ __align__(16) bf16 ldsB[128 * 64];

  const int tid  = threadIdx.x;
  const int lane = tid & 63;
  const int wave = tid >> 6;
  const int d = blockIdx.y * 64 + blockIdx.x;
  const int xcd = d & 7, slot = d >> 3;
  const int g = xcd * 8 + slot / 24;      // m-tile 0..63
  const int c = slot % 24;                // which*8 + n-tile
  const int which = c >> 3;
  const int n0 = (c & 7) * 128;
  const int m0 = g * 128;
  const bf16* Bt = Wb3 + (size_t)which * 1048576;
  const float* bias = (which == 0) ? bq : ((which == 1) ? bk : bv);

  const int l15  = lane & 15;
  const int quad = lane >> 4;
  const int wm = (wave >> 1) * 64;
  const int wn = (wave & 1) * 64;
  const int sw = l15 & 7;

  f32x4 acc[4][4];
#pragma unroll
  for (int i = 0; i < 4; ++i)
#pragma unroll
    for (int j = 0; j < 4; ++j) acc[i][j] = f32x4{0.f, 0.f, 0.f, 0.f};

  const int srow = tid >> 3;
  const int scol = ((tid & 7) ^ (srow & 7)) * 8;
  const size_t a_base = (size_t)(m0 + srow) * K + scol;
  const size_t b_base = (size_t)(n0 + srow) * K + scol;
  const int lds_off = tid * 8;

  for (int kt = 0; kt < K; kt += 64) {
    const bf16* ga = Xb + a_base + kt;
    const bf16* gb = Bt + b_base + kt;
#pragma unroll
    for (int it = 0; it < 4; ++it) {
      g2l16(ga + (size_t)(it * 32) * K, &ldsA[lds_off + it * 2048]);
      g2l16(gb + (size_t)(it * 32) * K, &ldsB[lds_off + it * 2048]);
    }
    __syncthreads();
#pragma unroll
    for (int ks = 0; ks < 2; ++ks) {
      const int ch = ks * 4 + quad;
      bf16x8 af[4], bfg[4];
#pragma unroll
      for (int i = 0; i < 4; ++i)
        af[i] = *(const bf16x8*)&ldsA[(wm + i * 16 + l15) * 64 + (ch ^ sw) * 8];
#pragma unroll
      for (int j = 0; j < 4; ++j)
        bfg[j] = *(const bf16x8*)&ldsB[(wn + j * 16 + l15) * 64 + (ch ^ sw) * 8];
#pragma unroll
      for (int i = 0; i < 4; ++i)
#pragma unroll
        for (int j = 0; j < 4; ++j)
          acc[i][j] = __builtin_amdgcn_mfma_f32_16x16x32_bf16(
              af[i], bfg[j], acc[i][j], 0, 0, 0);
    }
    __syncthreads();
  }

  // C/D layout: col = lane&15, row = quad*4 + reg [m89/m91]
  if (which < 2) {
    bf16* C = QK + (size_t)which * (size_t)(8192 * 1024);
#pragma unroll
    for (int i = 0; i < 4; ++i) {
#pragma unroll
      for (int j = 0; j < 4; ++j) {
        const int r = m0 + wm + i * 16 + quad * 4;
        const int cc = n0 + wn + j * 16 + l15;
        const float bvv = bias[cc];
        f32x4 v = acc[i][j];
#pragma unroll
        for (int reg = 0; reg < 4; ++reg)
          C[(size_t)(r + reg) * N + cc] = (bf16)(v[reg] + bvv);
      }
    }
  } else {
#pragma unroll
    for (int i = 0; i < 4; ++i) {
#pragma unroll
      for (int j = 0; j < 4; ++j) {
        const int r = m0 + wm + i * 16 + quad * 4;  // b*4096+s
        const int cc = n0 + wn + j * 16 + l15;      // h
        const int b = r >> 12, s = r & 4095;
        const float bvv = bias[cc];
        f32x4 v = acc[i][j];
        bf16x4 o;
#pragma unroll
        for (int reg = 0; reg < 4; ++reg) o[reg] = (bf16)(v[reg] + bvv);
        *(bf16x4*)&Vt[((size_t)(b * 1024 + cc)) * 4096 + s] = o;
      }
    }
  }
}

// ---------------- scores GEMM + fused exp/bitmask/row-sum ------------------
// grid (32, 16): x = m-tile (256), y = n-tile (256). Bitmask epilogue.
__global__ __launch_bounds__(512, 2) void gemm_scores(
    const bf16* __restrict__ Q, const bf16* __restrict__ Kb,
    const unsigned long long* __restrict__ BM, bf16* __restrict__ P,
    float* __restrict__ row_sum) {
  __shared__ __align__(16) bf16 lds[2 * 32768];  // 128 KiB
  const int bid = blockIdx.y * 32 + blockIdx.x;
  const int sb = (bid & 7) * 64 + (bid >> 3);
  const int bx = sb & 31, by = sb >> 5;
  const int m0 = bx * 256;
  const int n0 = by * 256;
  const int batch = m0 >> 12;
  const bf16* Ag = Q + (size_t)m0 * 1024;
  const bf16* Bg = Kb + (size_t)batch * (size_t)(4096 * 1024) +
                   (size_t)n0 * 1024;

  f32x4 acc[8][4];
#pragma unroll
  for (int i = 0; i < 8; ++i)
#pragma unroll
    for (int j = 0; j < 4; ++j) acc[i][j] = f32x4{0.f, 0.f, 0.f, 0.f};

  kloop256<16>(Ag, Bg, 1024, 1024, lds, acc);

  const int lane = threadIdx.x & 63, wave = threadIdx.x >> 6;
  const int l15 = lane & 15, quad = lane >> 4;
  const int wrow = (wave >> 2) * 128, wcol = (wave & 3) * 64;
  const int bmcol = (n0 + wcol) >> 6;   // u64 word index within row

#pragma unroll
  for (int i = 0; i < 8; ++i) {
    const int r = m0 + wrow + i * 16 + quad * 4;
    unsigned long long mrow[4];
#pragma unroll
    for (int reg = 0; reg < 4; ++reg)
      mrow[reg] = BM[(size_t)(r + reg) * 64 + bmcol];
    f32x4 rsum = f32x4{0.f, 0.f, 0.f, 0.f};
#pragma unroll
    for (int j = 0; j < 4; ++j) {
      const int c = n0 + wcol + j * 16 + l15;
      f32x4 v = acc[i][j];
#pragma unroll
      for (int reg = 0; reg < 4; ++reg) {
        float e = __expf(v[reg] * 0.03125f);
        if (((mrow[reg] >> (j * 16 + l15)) & 1ull) == 0) e = 0.f;
        P[(size_t)(r + reg) * 4096 + c] = (bf16)e;
        rsum[reg] += e;
      }
    }
#pragma unroll
    for (int off = 1; off < 16; off <<= 1) {
#pragma unroll
      for (int reg = 0; reg < 4; ++reg)
        rsum[reg] += __shfl_xor(rsum[reg], off);
    }
    if (l15 == 0) {
#pragma unroll
      for (int reg = 0; reg < 4; ++reg)
        atomicAdd(&row_sum[r + reg], rsum[reg]);
    }
  }
}

// ---------------- PV GEMM (R7 structure + m-grouped XCD swizzle) -----------
// 512 blocks: xcd=d%8, slot=d/8; g = xcd*8 + slot/8 (m-tile 0..63),
// h = slot%8 (n-tile). All 8 n-blocks of a P-panel on one XCD consecutively.
__global__ __launch_bounds__(256, 2) void gemm_pv(
    const bf16* __restrict__ A, const bf16* __restrict__ Bt,
    const float* __restrict__ row_sum, float* __restrict__ C)
{
  constexpr int N = 1024, K = 4096;
  __shared__ __align__(16) bf16 ldsA[128 * 64];
  __shared__ __align__(16) bf16 ldsB[128 * 64];

  const int tid  = threadIdx.x;
  const int lane = tid & 63;
  const int wave = tid >> 6;
  const int d = blockIdx.y * 64 + blockIdx.x;
  const int xcd = d & 7, slot = d >> 3;
  const int g = xcd * 8 + (slot >> 3);   // m-tile 0..63
  const int h = slot & 7;                // n-tile 0..7
  const int m0 = g * 128;
  const int n0 = h * 128;
  const int batch = m0 >> 12;
  const bf16* Btb = Bt + (size_t)batch * (size_t)(1024 * 4096);

  const int l15  = lane & 15;
  const int quad = lane >> 4;
  const int wm = (wave >> 1) * 64;
  const int wn = (wave & 1) * 64;
  const int sw = l15 & 7;

  f32x4 acc[4][4];
#pragma unroll
  for (int i = 0; i < 4; ++i)
#pragma unroll
    for (int j = 0; j < 4; ++j) acc[i][j] = f32x4{0.f, 0.f, 0.f, 0.f};

  const int srow = tid >> 3;
  const int scol = ((tid & 7) ^ (srow & 7)) * 8;
  const size_t a_base = (size_t)(m0 + srow) * K + scol;
  const size_t b_base = (size_t)(n0 + srow) * K + scol;
  const int lds_off = tid * 8;

  for (int kt = 0; kt < K; kt += 64) {
    const bf16* ga = A + a_base + kt;
    const bf16* gb = Btb + b_base + kt;
#pragma unroll
    for (int it = 0; it < 4; ++it) {
      g2l16(ga + (size_t)(it * 32) * K, &ldsA[lds_off + it * 2048]);
      g2l16(gb + (size_t)(it * 32) * K, &ldsB[lds_off + it * 2048]);
    }
    __syncthreads();
#pragma unroll
    for (int ks = 0; ks < 2; ++ks) {
      const int ch = ks * 4 + quad;
      bf16x8 af[4], bfg[4];
#pragma unroll
      for (int i = 0; i < 4; ++i)
        af[i] = *(const bf16x8*)&ldsA[(wm + i * 16 + l15) * 64 + (ch ^ sw) * 8];
#pragma unroll
      for (int j = 0; j < 4; ++j)
        bfg[j] = *(const bf16x8*)&ldsB[(wn + j * 16 + l15) * 64 + (ch ^ sw) * 8];
#pragma unroll
      for (int i = 0; i < 4; ++i)
#pragma unroll
        for (int j = 0; j < 4; ++j)
          acc[i][j] = __builtin_amdgcn_mfma_f32_16x16x32_bf16(
              af[i], bfg[j], acc[i][j], 0, 0, 0);
    }
    __syncthreads();
  }

#pragma unroll
  for (int i = 0; i < 4; ++i) {
    const int r = m0 + wm + i * 16 + quad * 4;
    f32x4 inv;
#pragma unroll
    for (int reg = 0; reg < 4; ++reg) inv[reg] = 1.0f / row_sum[r + reg];
#pragma unroll
    for (int j = 0; j < 4; ++j) {
      const int c = n0 + wn + j * 16 + l15;
      f32x4 v = acc[i][j];
#pragma unroll
      for (int reg = 0; reg < 4; ++reg)
        C[(size_t)(r + reg) * N + c] = v[reg] * inv[reg];
    }
  }
}

extern "C" void kernel_launch(void* const* d_in, const int* in_sizes, int n_in,
                              void* d_out, int out_size, void* d_ws,
                              size_t ws_size, hipStream_t stream) {
  const float* X   = (const float*)d_in[0];
  const int* mask  = (const int*)d_in[1];
  const float* Wq  = (const float*)d_in[2];
  const float* bq  = (const float*)d_in[3];
  const float* Wk  = (const float*)d_in[4];
  const float* bk  = (const float*)d_in[5];
  const float* Wv  = (const float*)d_in[6];
  const float* bv  = (const float*)d_in[7];
  float* out = (float*)d_out;

  // ws layout (128 MiB): [0,16M) Q  [16M,32M) K  [32M,48M) X_bf
  //   [48M,64M) Vt  [64M,128M) Sc/P (first 6 MiB aliased by W_bf).
  //   X_bf region is dead after gemm_qkv; it then hosts row_sum (32 KB at
  //   +0) and the 4 MB bitmask (at +64 KB). pack_mask runs after gemm_qkv.
  const size_t QKV_ELEMS = (size_t)8192 * 1024;
  bf16* Q    = (bf16*)d_ws;
  bf16* Kb   = Q + QKV_ELEMS;
  bf16* X_bf = Kb + QKV_ELEMS;
  bf16* Vt   = X_bf + QKV_ELEMS;
  bf16* Sc   = Vt + QKV_ELEMS;
  bf16* W_bf = Sc;
  float* row_sum = (float*)X_bf;  // 8192 floats (32 KB)
  unsigned long long* BM =
      (unsigned long long*)((char*)X_bf + 65536);  // 4 MB bitmask

  cvt_f32_bf16<<<dim3(4096), dim3(256), 0, stream>>>(X, X_bf, 8388608);
  cvt_w3<<<dim3(1536), dim3(256), 0, stream>>>(Wq, Wk, Wv, W_bf);
  gemm_qkv<<<dim3(64, 24), dim3(256), 0, stream>>>(X_bf, W_bf, bq, bk, bv, Q,
                                                   Vt);
  // X_bf dead from here; reuse for row_sum + bitmask.
  pack_mask<<<dim3(2048), dim3(256), 0, stream>>>(mask, BM, 33554432);
  hipMemsetAsync(row_sum, 0, 8192 * sizeof(float), stream);
  gemm_scores<<<dim3(32, 16), dim3(512), 0, stream>>>(Q, Kb, BM, Sc,
                                                      row_sum);
  gemm_pv<<<dim3(64, 8), dim3(256), 0, stream>>>(Sc, Vt, row_sum, out);
}

// Round 8
// 414.626 us; speedup vs baseline: 1.2486x; 1.1006x over previous
//
#include <hip/hip_runtime.h>
#include <stdint.h>

// SelfAttention B=2,S=4096,E=1024,H=1024. f32 in, f32 out, bf16 MFMA inside.
// R15: fixed-cost consolidation (K-loops at their ~600-680 TF session
//   plateau; recoverable time is in fixed costs, per R11-vs-R14 evidence):
//   - pack_mask REMOVED (net -24us: scores+pack 138 vs R11's fused 114.8).
//     scores back to R11-exact int32-mask epilogue.
//   - memset+atomics REMOVED: scores writes race-free PARTIAL row sums
//     psum[(ntile*4 + wavecol)][row] (2 MB, X_bf region dead after qkv, every
//     slot written exactly once -> no init needed). pv reduces 64 partials
//     per row cooperatively into LDS once per block.
//   - cvt kernels fused. 7 launches -> 4 (graph gap reduction).
//   - qkv/pv keep R14 m-grouped XCD assignment (pv <=110 vs R12's 148).
// R14 post-mortem: mask-traffic removal bought 4us (epilogue is NOT
//   burst-memory-bound); pack_mask itself cost 28us. Net loss.

typedef __bf16 bf16;
typedef __attribute__((ext_vector_type(4))) __bf16 bf16x4;
typedef __attribute__((ext_vector_type(8))) __bf16 bf16x8;
typedef __attribute__((ext_vector_type(4))) float f32x4;

__device__ __forceinline__ void g2l16(const void* g, void* l) {
  __builtin_amdgcn_global_load_lds(
      (const __attribute__((address_space(1))) uint32_t*)g,
      (__attribute__((address_space(3))) uint32_t*)l, 16, 0, 0);
}

__device__ __forceinline__ f32x4 ds_read128(uint32_t addr) {
  f32x4 d;
  asm volatile("ds_read_b128 %0, %1" : "=v"(d) : "v"(addr));
  return d;
}

template <int V> struct IC { static constexpr int value = V; };
template <bool V> struct BC { static constexpr bool value = V; };

template <int N> __device__ __forceinline__ void waitvm() {
  if constexpr (N == 6) asm volatile("s_waitcnt vmcnt(6)" ::: "memory");
  else if constexpr (N == 4) asm volatile("s_waitcnt vmcnt(4)" ::: "memory");
  else if constexpr (N == 0) asm volatile("s_waitcnt vmcnt(0)" ::: "memory");
}

// ---------------- fused f32 -> bf16 converter (X + Wq|Wk|Wv) ---------------
__global__ __launch_bounds__(256) void cvt_all(
    const float* __restrict__ X, const float* __restrict__ Wq,
    const float* __restrict__ Wk, const float* __restrict__ Wv,
    bf16* __restrict__ X_bf, bf16* __restrict__ W_bf) {
  const int bid = blockIdx.x;
  const float* src;
  bf16* dst;
  int i;
  if (bid < 4096) {                       // X: 8388608 elems
    i = (bid * 256 + threadIdx.x) * 8;
    src = X; dst = X_bf;
  } else {                                // W3: 3*1048576 elems
    i = ((bid - 4096) * 256 + threadIdx.x) * 8;
    const int seg = i >> 20;
    const int off = i & 1048575;
    src = (seg == 0) ? Wq : (seg == 1) ? Wk : Wv;
    dst = W_bf;
    f32x4 a = *(const f32x4*)(src + off);
    f32x4 b = *(const f32x4*)(src + off + 4);
    bf16x8 o;
#pragma unroll
    for (int e = 0; e < 4; ++e) { o[e] = (bf16)a[e]; o[4 + e] = (bf16)b[e]; }
    *(bf16x8*)(dst + i) = o;
    return;
  }
  f32x4 a = *(const f32x4*)(src + i);
  f32x4 b = *(const f32x4*)(src + i + 4);
  bf16x8 o;
#pragma unroll
  for (int e = 0; e < 4; ++e) { o[e] = (bf16)a[e]; o[4 + e] = (bf16)b[e]; }
  *(bf16x8*)(dst + i) = o;
}

// ======================= kloop256: BM=256 x BN=256, BK=64 (scores) =========
// R11 form: asm ds_read_b128, counted vmcnt(6), 4 phases/K-tile, 2 buffers.
template <int NT>
__device__ __forceinline__ void kloop256(
    const bf16* __restrict__ Ag, const bf16* __restrict__ Bg, const int KA,
    const int KB, bf16* lds, f32x4 (&acc)[8][4]) {
  const int tid = threadIdx.x;
  const int lane = tid & 63;
  const int wave = tid >> 6;
  const int l15 = lane & 15, quad = lane >> 4;
  const int wrow = (wave >> 2) * 128;
  const int wcol = (wave & 3) * 64;
  const int srow = tid >> 3;
  const int scol = ((tid & 7) ^ (srow & 7)) * 8;
  const int swz = l15 & 7;

  const uint32_t lds_u = (uint32_t)(uintptr_t)lds;
  const uint32_t a_l15 = lds_u + (uint32_t)((wrow + l15) * 128);
  const uint32_t b_l15 = lds_u + 32768u + (uint32_t)((wcol + l15) * 128);
  const uint32_t ck0 = (uint32_t)(((quad) ^ swz) * 16);
  const uint32_t ck1 = (uint32_t)(((4 + quad) ^ swz) * 16);

  auto stg = [&](int t, int h) {
    bf16* base = lds + (t & 1) * 32768;
    if (h == 0) {
      const bf16* g = Bg + (size_t)srow * KB + t * 64 + scol;
      g2l16(g, base + 16384 + tid * 8);
      g2l16(g + (size_t)64 * KB, base + 16384 + tid * 8 + 4096);
    } else if (h == 1) {
      const bf16* g = Bg + (size_t)(128 + srow) * KB + t * 64 + scol;
      g2l16(g, base + 24576 + tid * 8);
      g2l16(g + (size_t)64 * KB, base + 24576 + tid * 8 + 4096);
    } else if (h == 2) {
      const bf16* g = Ag + (size_t)srow * KA + t * 64 + scol;
      g2l16(g, base + tid * 8);
      g2l16(g + (size_t)128 * KA, base + tid * 8 + 8192);
    } else {
      const bf16* g = Ag + (size_t)(64 + srow) * KA + t * 64 + scol;
      g2l16(g, base + 4096 + tid * 8);
      g2l16(g + (size_t)128 * KA, base + 4096 + tid * 8 + 8192);
    }
  };

  f32x4 brf[2][4];
  auto phase = [&](int t, auto qc, int st, int sh, auto dsc, auto vmc) {
    constexpr int q = decltype(qc)::value;
    constexpr bool ds = decltype(dsc)::value;
    constexpr int vm = decltype(vmc)::value;
    const uint32_t bb = (t & 1) ? 65536u : 0u;
    f32x4 ar[2][2];
#pragma unroll
    for (int i = 0; i < 2; ++i) {
      ar[i][0] = ds_read128(a_l15 + bb + (uint32_t)((2 * q + i) * 2048) + ck0);
      ar[i][1] = ds_read128(a_l15 + bb + (uint32_t)((2 * q + i) * 2048) + ck1);
    }
    if constexpr (q == 0) {
#pragma unroll
      for (int j = 0; j < 4; ++j) {
        brf[0][j] = ds_read128(b_l15 + bb + (uint32_t)(j * 2048) + ck0);
        brf[1][j] = ds_read128(b_l15 + bb + (uint32_t)(j * 2048) + ck1);
      }
    }
    if constexpr (ds) stg(st, sh);
    __builtin_amdgcn_s_barrier();
    asm volatile("s_waitcnt lgkmcnt(0)" ::: "memory");
    __builtin_amdgcn_sched_barrier(0);
    __builtin_amdgcn_s_setprio(1);
#pragma unroll
    for (int ks = 0; ks < 2; ++ks)
#pragma unroll
      for (int i = 0; i < 2; ++i)
#pragma unroll
        for (int j = 0; j < 4; ++j)
          acc[2 * q + i][j] = __builtin_amdgcn_mfma_f32_16x16x32_bf16(
              __builtin_bit_cast(bf16x8, ar[i][ks]),
              __builtin_bit_cast(bf16x8, brf[ks][j]),
              acc[2 * q + i][j], 0, 0, 0);
    __builtin_amdgcn_s_setprio(0);
    waitvm<vm>();
    __builtin_amdgcn_s_barrier();
  };

  stg(0, 0); stg(0, 1); stg(0, 2); stg(0, 3);
  stg(1, 0); stg(1, 1); stg(1, 2);
  asm volatile("s_waitcnt vmcnt(6)" ::: "memory");
  __builtin_amdgcn_s_barrier();

  constexpr int NI = NT / 2;
#pragma unroll 1
  for (int u = 0; u < NI - 1; ++u) {
    const int t0 = 2 * u, t1 = t0 + 1;
    phase(t0, IC<0>{}, t1, 3, BC<true>{}, IC<-1>{});
    phase(t0, IC<1>{}, t0 + 2, 0, BC<true>{}, IC<-1>{});
    phase(t0, IC<2>{}, t0 + 2, 1, BC<true>{}, IC<-1>{});
    phase(t0, IC<3>{}, t0 + 2, 2, BC<true>{}, IC<6>{});
    phase(t1, IC<0>{}, t0 + 2, 3, BC<true>{}, IC<-1>{});
    phase(t1, IC<1>{}, t0 + 3, 0, BC<true>{}, IC<-1>{});
    phase(t1, IC<2>{}, t0 + 3, 1, BC<true>{}, IC<-1>{});
    phase(t1, IC<3>{}, t0 + 3, 2, BC<true>{}, IC<6>{});
  }
  {
    const int t0 = NT - 2, t1 = NT - 1;
    phase(t0, IC<0>{}, t1, 3, BC<true>{}, IC<-1>{});
    phase(t0, IC<1>{}, 0, 0, BC<false>{}, IC<-1>{});
    phase(t0, IC<2>{}, 0, 0, BC<false>{}, IC<-1>{});
    phase(t0, IC<3>{}, 0, 0, BC<false>{}, IC<0>{});
    phase(t1, IC<0>{}, 0, 0, BC<false>{}, IC<-1>{});
    phase(t1, IC<1>{}, 0, 0, BC<false>{}, IC<-1>{});
    phase(t1, IC<2>{}, 0, 0, BC<false>{}, IC<-1>{});
    phase(t1, IC<3>{}, 0, 0, BC<false>{}, IC<-1>{});
  }
}

// ---------------- fused QKV GEMM (R7 structure + m-grouped XCD swizzle) ----
// 1536 blocks: xcd=d%8, slot=d/8; g = xcd*8 + slot/24 (m-tile), c = slot%24
// (which*8 + n-tile). All 24 n-blocks of an X-panel run on one XCD.
__global__ __launch_bounds__(256, 2) void gemm_qkv(
    const bf16* __restrict__ Xb, const bf16* __restrict__ Wb3,
    const float* __restrict__ bq, const float* __restrict__ bk,
    const float* __restrict__ bv, bf16* __restrict__ QK,
    bf16* __restrict__ Vt)
{
  constexpr int K = 1024, N = 1024;
  __shared__ __align__(16) bf16 ldsA[128 * 64];
  __shared__ __align__(16) bf16 ldsB[128 * 64];

  const int tid  = threadIdx.x;
  const int lane = tid & 63;
  const int wave = tid >> 6;
  const int d = blockIdx.y * 64 + blockIdx.x;
  const int xcd = d & 7, slot = d >> 3;
  const int g = xcd * 8 + slot / 24;      // m-tile 0..63
  const int c = slot % 24;                // which*8 + n-tile
  const int which = c >> 3;
  const int n0 = (c & 7) * 128;
  const int m0 = g * 128;
  const bf16* Bt = Wb3 + (size_t)which * 1048576;
  const float* bias = (which == 0) ? bq : ((which == 1) ? bk : bv);

  const int l15  = lane & 15;
  const int quad = lane >> 4;
  const int wm = (wave >> 1) * 64;
  const int wn = (wave & 1) * 64;
  const int sw = l15 & 7;

  f32x4 acc[4][4];
#pragma unroll
  for (int i = 0; i < 4; ++i)
#pragma unroll
    for (int j = 0; j < 4; ++j) acc[i][j] = f32x4{0.f, 0.f, 0.f, 0.f};

  const int srow = tid >> 3;
  const int scol = ((tid & 7) ^ (srow & 7)) * 8;
  const size_t a_base = (size_t)(m0 + srow) * K + scol;
  const size_t b_base = (size_t)(n0 + srow) * K + scol;
  const int lds_off = tid * 8;

  for (int kt = 0; kt < K; kt += 64) {
    const bf16* ga = Xb + a_base + kt;
    const bf16* gb = Bt + b_base + kt;
#pragma unroll
    for (int it = 0; it < 4; ++it) {
      g2l16(ga + (size_t)(it * 32) * K, &ldsA[lds_off + it * 2048]);
      g2l16(gb + (size_t)(it * 32) * K, &ldsB[lds_off + it * 2048]);
    }
    __syncthreads();
#pragma unroll
    for (int ks = 0; ks < 2; ++ks) {
      const int ch = ks * 4 + quad;
      bf16x8 af[4], bfg[4];
#pragma unroll
      for (int i = 0; i < 4; ++i)
        af[i] = *(const bf16x8*)&ldsA[(wm + i * 16 + l15) * 64 + (ch ^ sw) * 8];
#pragma unroll
      for (int j = 0; j < 4; ++j)
        bfg[j] = *(const bf16x8*)&ldsB[(wn + j * 16 + l15) * 64 + (ch ^ sw) * 8];
#pragma unroll
      for (int i = 0; i < 4; ++i)
#pragma unroll
        for (int j = 0; j < 4; ++j)
          acc[i][j] = __builtin_amdgcn_mfma_f32_16x16x32_bf16(
              af[i], bfg[j], acc[i][j], 0, 0, 0);
    }
    __syncthreads();
  }

  // C/D layout: col = lane&15, row = quad*4 + reg [m89/m91]
  if (which < 2) {
    bf16* C = QK + (size_t)which * (size_t)(8192 * 1024);
#pragma unroll
    for (int i = 0; i < 4; ++i) {
#pragma unroll
      for (int j = 0; j < 4; ++j) {
        const int r = m0 + wm + i * 16 + quad * 4;
        const int cc = n0 + wn + j * 16 + l15;
        const float bvv = bias[cc];
        f32x4 v = acc[i][j];
#pragma unroll
        for (int reg = 0; reg < 4; ++reg)
          C[(size_t)(r + reg) * N + cc] = (bf16)(v[reg] + bvv);
      }
    }
  } else {
#pragma unroll
    for (int i = 0; i < 4; ++i) {
#pragma unroll
      for (int j = 0; j < 4; ++j) {
        const int r = m0 + wm + i * 16 + quad * 4;  // b*4096+s
        const int cc = n0 + wn + j * 16 + l15;      // h
        const int b = r >> 12, s = r & 4095;
        const float bvv = bias[cc];
        f32x4 v = acc[i][j];
        bf16x4 o;
#pragma unroll
        for (int reg = 0; reg < 4; ++reg) o[reg] = (bf16)(v[reg] + bvv);
        *(bf16x4*)&Vt[((size_t)(b * 1024 + cc)) * 4096 + s] = o;
      }
    }
  }
}

// ---------------- scores GEMM + fused exp/mask/partial-row-sum -------------
// grid (32, 16). Writes psum[(by*4 + wavecol)*8192 + r] partials: every slot
// written exactly once (by 0..15 x wavecol 0..3 x all rows) -> no init, no
// atomics. Mask read int32 in-epilogue (R11-proven).
__global__ __launch_bounds__(512, 2) void gemm_scores(
    const bf16* __restrict__ Q, const bf16* __restrict__ Kb,
    const int* __restrict__ mask, bf16* __restrict__ P,
    float* __restrict__ psum) {
  __shared__ __align__(16) bf16 lds[2 * 32768];  // 128 KiB
  const int bid = blockIdx.y * 32 + blockIdx.x;
  const int sb = (bid & 7) * 64 + (bid >> 3);
  const int bx = sb & 31, by = sb >> 5;
  const int m0 = bx * 256;
  const int n0 = by * 256;
  const int batch = m0 >> 12;
  const bf16* Ag = Q + (size_t)m0 * 1024;
  const bf16* Bg = Kb + (size_t)batch * (size_t)(4096 * 1024) +
                   (size_t)n0 * 1024;

  f32x4 acc[8][4];
#pragma unroll
  for (int i = 0; i < 8; ++i)
#pragma unroll
    for (int j = 0; j < 4; ++j) acc[i][j] = f32x4{0.f, 0.f, 0.f, 0.f};

  kloop256<16>(Ag, Bg, 1024, 1024, lds, acc);

  const int lane = threadIdx.x & 63, wave = threadIdx.x >> 6;
  const int l15 = lane & 15, quad = lane >> 4;
  const int wrow = (wave >> 2) * 128, wcol = (wave & 3) * 64;
  float* ps = psum + (size_t)(by * 4 + (wave & 3)) * 8192;

#pragma unroll
  for (int i = 0; i < 8; ++i) {
    const int r = m0 + wrow + i * 16 + quad * 4;
    f32x4 rsum = f32x4{0.f, 0.f, 0.f, 0.f};
#pragma unroll
    for (int j = 0; j < 4; ++j) {
      const int c = n0 + wcol + j * 16 + l15;
      f32x4 v = acc[i][j];
#pragma unroll
      for (int reg = 0; reg < 4; ++reg) {
        float e = __expf(v[reg] * 0.03125f);
        if (mask[(size_t)(r + reg) * 4096 + c] == 0) e = 0.f;
        P[(size_t)(r + reg) * 4096 + c] = (bf16)e;
        rsum[reg] += e;
      }
    }
#pragma unroll
    for (int off = 1; off < 16; off <<= 1) {
#pragma unroll
      for (int reg = 0; reg < 4; ++reg)
        rsum[reg] += __shfl_xor(rsum[reg], off);
    }
    if (l15 == 0) {
#pragma unroll
      for (int reg = 0; reg < 4; ++reg) ps[r + reg] = rsum[reg];
    }
  }
}

// ---------------- PV GEMM (R7 structure + m-grouped XCD swizzle) -----------
// 512 blocks: xcd=d%8, slot=d/8; g = xcd*8 + slot/8 (m-tile), h = slot%8.
// Epilogue: cooperative psum reduction (64 partials/row) into LDS, then
// out = acc * (1/row_sum).
__global__ __launch_bounds__(256, 2) void gemm_pv(
    const bf16* __restrict__ A, const bf16* __restrict__ Bt,
    const float* __restrict__ psum, float* __restrict__ C)
{
  constexpr int N = 1024, K = 4096;
  __shared__ __align__(16) bf16 ldsA[128 * 64];
  __shared__ __align__(16) bf16 ldsB[128 * 64];

  const int tid  = threadIdx.x;
  const int lane = tid & 63;
  const int wave = tid >> 6;
  const int d = blockIdx.y * 64 + blockIdx.x;
  const int xcd = d & 7, slot = d >> 3;
  const int g = xcd * 8 + (slot >> 3);   // m-tile 0..63
  const int h = slot & 7;                // n-tile 0..7
  const int m0 = g * 128;
  const int n0 = h * 128;
  const int batch = m0 >> 12;
  const bf16* Btb = Bt + (size_t)batch * (size_t)(1024 * 4096);

  const int l15  = lane & 15;
  const int quad = lane >> 4;
  const int wm = (wave >> 1) * 64;
  const int wn = (wave & 1) * 64;
  const int sw = l15 & 7;

  f32x4 acc[4][4];
#pragma unroll
  for (int i = 0; i < 4; ++i)
#pragma unroll
    for (int j = 0; j < 4; ++j) acc[i][j] = f32x4{0.f, 0.f, 0.f, 0.f};

  const int srow = tid >> 3;
  const int scol = ((tid & 7) ^ (srow & 7)) * 8;
  const size_t a_base = (size_t)(m0 + srow) * K + scol;
  const size_t b_base = (size_t)(n0 + srow) * K + scol;
  const int lds_off = tid * 8;

  for (int kt = 0; kt < K; kt += 64) {
    const bf16* ga = A + a_base + kt;
    const bf16* gb = Btb + b_base + kt;
#pragma unroll
    for (int it = 0; it < 4; ++it) {
      g2l16(ga + (size_t)(it * 32) * K, &ldsA[lds_off + it * 2048]);
      g2l16(gb + (size_t)(it * 32) * K, &ldsB[lds_off + it * 2048]);
    }
    __syncthreads();
#pragma unroll
    for (int ks = 0; ks < 2; ++ks) {
      const int ch = ks * 4 + quad;
      bf16x8 af[4], bfg[4];
#pragma unroll
      for (int i = 0; i < 4; ++i)
        af[i] = *(const bf16x8*)&ldsA[(wm + i * 16 + l15) * 64 + (ch ^ sw) * 8];
#pragma unroll
      for (int j = 0; j < 4; ++j)
        bfg[j] = *(const bf16x8*)&ldsB[(wn + j * 16 + l15) * 64 + (ch ^ sw) * 8];
#pragma unroll
      for (int i = 0; i < 4; ++i)
#pragma unroll
        for (int j = 0; j < 4; ++j)
          acc[i][j] = __builtin_amdgcn_mfma_f32_16x16x32_bf16(
              af[i], bfg[j], acc[i][j], 0, 0, 0);
    }
    __syncthreads();
  }

  // Cooperative row-sum reduction: 64 partials per row -> 1/sum in LDS.
  float* linv = (float*)ldsA;   // K-loop LDS dead (loop ends with barrier)
  if (tid < 128) {
    float s = 0.f;
#pragma unroll 8
    for (int p = 0; p < 64; ++p) s += psum[(size_t)p * 8192 + m0 + tid];
    linv[tid] = 1.0f / s;
  }
  __syncthreads();

#pragma unroll
  for (int i = 0; i < 4; ++i) {
    const int lr = wm + i * 16 + quad * 4;   // local row
    const int r = m0 + lr;
    f32x4 inv;
#pragma unroll
    for (int reg = 0; reg < 4; ++reg) inv[reg] = linv[lr + reg];
#pragma unroll
    for (int j = 0; j < 4; ++j) {
      const int c = n0 + wn + j * 16 + l15;
      f32x4 v = acc[i][j];
#pragma unroll
      for (int reg = 0; reg < 4; ++reg)
        C[(size_t)(r + reg) * N + c] = v[reg] * inv[reg];
    }
  }
}

extern "C" void kernel_launch(void* const* d_in, const int* in_sizes, int n_in,
                              void* d_out, int out_size, void* d_ws,
                              size_t ws_size, hipStream_t stream) {
  const float* X   = (const float*)d_in[0];
  const int* mask  = (const int*)d_in[1];
  const float* Wq  = (const float*)d_in[2];
  const float* bq  = (const float*)d_in[3];
  const float* Wk  = (const float*)d_in[4];
  const float* bk  = (const float*)d_in[5];
  const float* Wv  = (const float*)d_in[6];
  const float* bv  = (const float*)d_in[7];
  float* out = (float*)d_out;

  // ws layout (128 MiB): [0,16M) Q  [16M,32M) K  [32M,48M) X_bf
  //   [48M,64M) Vt  [64M,128M) Sc/P (first 6 MiB aliased by W_bf, dead
  //   after qkv).  psum (2 MB, 64x8192 f32) aliases X_bf (dead after qkv;
  //   every slot written by scores before pv reads -> no init).
  const size_t QKV_ELEMS = (size_t)8192 * 1024;
  bf16* Q    = (bf16*)d_ws;
  bf16* Kb   = Q + QKV_ELEMS;
  bf16* X_bf = Kb + QKV_ELEMS;
  bf16* Vt   = X_bf + QKV_ELEMS;
  bf16* Sc   = Vt + QKV_ELEMS;
  bf16* W_bf = Sc;
  float* psum = (float*)X_bf;  // 64 * 8192 floats = 2 MB

  cvt_all<<<dim3(5632), dim3(256), 0, stream>>>(X, Wq, Wk, Wv, X_bf, W_bf);
  gemm_qkv<<<dim3(64, 24), dim3(256), 0, stream>>>(X_bf, W_bf, bq, bk, bv, Q,
                                                   Vt);
  gemm_scores<<<dim3(32, 16), dim3(512), 0, stream>>>(Q, Kb, mask, Sc, psum);
  gemm_pv<<<dim3(64, 8), dim3(256), 0, stream>>>(Sc, Vt, psum, out);
}